// Round 9
// baseline (436.741 us; speedup 1.0000x reference)
//
#include <hip/hip_runtime.h>
#include <hip/hip_bf16.h>
#include <math.h>

#define NN 20000
#define EE 320000
#define DIN 64
#define HIDC 128
#define NCOLS 1664   // 512 q | 1024 kv(fp8) | 128 skip
#define NL 3

typedef __attribute__((ext_vector_type(8))) short bf16x8;
typedef __attribute__((ext_vector_type(8))) unsigned short u16x8;
typedef __attribute__((ext_vector_type(4))) float f32x4;

__device__ __forceinline__ float bf2f(unsigned short u) {
  union { unsigned i; float f; } v; v.i = ((unsigned)u) << 16; return v.f;
}
__device__ __forceinline__ unsigned short f2bf(float f) {
  __hip_bfloat16 b = __float2bfloat16(f);
  return *(unsigned short*)&b;
}

// ---- fp8 e4m3fn (OCP) encode/decode, HW cvt when available ----
__device__ __forceinline__ unsigned char f2fp8(float f) {
#if __has_builtin(__builtin_amdgcn_cvt_pk_fp8_f32)
  return (unsigned char)(__builtin_amdgcn_cvt_pk_fp8_f32(f, f, 0, 0) & 0xFF);
#else
  unsigned b = __float_as_uint(f);
  unsigned s = (b >> 24) & 0x80u;
  float a = fabsf(f);
  if (a < 0.015625f) return (unsigned char)s;
  unsigned mag = __float_as_uint(fminf(a, 448.f));
  mag += 0x7FFFFu + ((mag >> 20) & 1u);
  unsigned code = (mag >> 20) - (120u << 3);
  if (code > 0x7Eu) code = 0x7Eu;
  return (unsigned char)(s | code);
#endif
}

__device__ __forceinline__ float fp82f(unsigned b) {
  unsigned x = ((b & 0x80u) << 24) | ((b & 0x7fu) << 20);
  return __uint_as_float(x) * 0x1p+120f;
}

__device__ __forceinline__ void dec8(uint2 u, float* f) {
#if __has_builtin(__builtin_amdgcn_cvt_pk_f32_fp8)
  {
    auto p0 = __builtin_amdgcn_cvt_pk_f32_fp8(u.x, 0);
    auto p1 = __builtin_amdgcn_cvt_pk_f32_fp8(u.x, 1);
    auto p2 = __builtin_amdgcn_cvt_pk_f32_fp8(u.y, 0);
    auto p3 = __builtin_amdgcn_cvt_pk_f32_fp8(u.y, 1);
    f[0] = p0[0]; f[1] = p0[1]; f[2] = p1[0]; f[3] = p1[1];
    f[4] = p2[0]; f[5] = p2[1]; f[6] = p3[0]; f[7] = p3[1];
  }
#else
#pragma unroll
  for (int i = 0; i < 4; i++) f[i] = fp82f((u.x >> (8 * i)) & 0xFFu);
#pragma unroll
  for (int i = 0; i < 4; i++) f[4 + i] = fp82f((u.y >> (8 * i)) & 0xFFu);
#endif
}

// ---------------- weight/bias/input prep (all layers at once) ----------------
__global__ void build_wcatT_all(const float* __restrict__ Wq, const float* __restrict__ Wk,
                                const float* __restrict__ Wv, const float* __restrict__ Wsk,
                                unsigned short* __restrict__ wT) {
  int idx = blockIdx.x * 256 + threadIdx.x;
  if (idx >= NL * NCOLS * HIDC) return;
  int l = idx / (NCOLS * HIDC);
  int rem = idx - l * (NCOLS * HIDC);
  int n = rem >> 7, k = rem & 127;
  float v;
  if (n < 512)       v = Wq[(size_t)l * HIDC * 512 + (size_t)k * 512 + n];
  else if (n < 1024) v = Wk[(size_t)l * HIDC * 512 + (size_t)k * 512 + (n - 512)];
  else if (n < 1536) v = Wv[(size_t)l * HIDC * 512 + (size_t)k * 512 + (n - 1024)];
  else               v = Wsk[(size_t)l * HIDC * HIDC + (size_t)k * 128 + (n - 1536)];
  wT[idx] = f2bf(v);
}

__global__ void build_bcat_all(const float* __restrict__ bq, const float* __restrict__ bk,
                               const float* __restrict__ bv, const float* __restrict__ bsk,
                               float* __restrict__ bcat) {
  int idx = blockIdx.x * 256 + threadIdx.x;
  if (idx >= NL * NCOLS) return;
  int l = idx / NCOLS, m = idx - l * NCOLS;
  float v;
  if (m < 512)       v = bq[l * 512 + m];
  else if (m < 1024) v = bk[l * 512 + (m - 512)];
  else if (m < 1536) v = bv[l * 512 + (m - 1024)];
  else               v = bsk[l * 128 + (m - 1536)];
  bcat[idx] = v;
}

__global__ void build_winT(const float* __restrict__ Win, unsigned short* __restrict__ winT) {
  int idx = blockIdx.x * 256 + threadIdx.x;
  if (idx >= HIDC * DIN) return;
  int c = idx >> 6, k = idx & 63;
  winT[idx] = f2bf(Win[(size_t)k * HIDC + c]);
}

__global__ void conv_x(const float* __restrict__ x, unsigned short* __restrict__ xb) {
  int i = blockIdx.x * 256 + threadIdx.x;
  if (i * 4 >= NN * DIN) return;
  float4 v = *(const float4*)(x + (size_t)i * 4);
  ushort4 o = make_ushort4(f2bf(v.x), f2bf(v.y), f2bf(v.z), f2bf(v.w));
  *(ushort4*)(xb + (size_t)i * 4) = o;
}

// ---------------- CSR build + degree sort ----------------
__global__ void deg_hist(const int* __restrict__ ei, int* __restrict__ deg) {
  int e = blockIdx.x * 256 + threadIdx.x;
  if (e >= EE) return;
  atomicAdd(&deg[ei[EE + e]], 1);
}

__global__ __launch_bounds__(1024) void scan_deg(const int* __restrict__ deg,
                                                 int* __restrict__ rowstart) {
  __shared__ int part[1024];
  int t = threadIdx.x;
  int base = t * 20;
  int local[20];
  int s = 0;
#pragma unroll
  for (int i = 0; i < 20; i++) {
    int idx = base + i;
    int d = (idx < NN) ? deg[idx] : 0;
    local[i] = d;
    s += d;
  }
  part[t] = s;
  __syncthreads();
  for (int d = 1; d < 1024; d <<= 1) {
    int v = (t >= d) ? part[t - d] : 0;
    __syncthreads();
    part[t] += v;
    __syncthreads();
  }
  int run = part[t] - s;
#pragma unroll
  for (int i = 0; i < 20; i++) {
    int idx = base + i;
    if (idx < NN) rowstart[idx] = run;
    run += local[i];
  }
  if (t == 1023) rowstart[NN] = part[1023];
}

// CSR entries = byte offsets into kv8 (src * 1024)
__global__ void csr_scatter(const int* __restrict__ ei, const int* __restrict__ rowstart,
                            int* __restrict__ cur, int* __restrict__ csrc) {
  int e = blockIdx.x * 256 + threadIdx.x;
  if (e >= EE) return;
  int src = ei[e], dst = ei[EE + e];
  int pos = atomicAdd(&cur[dst], 1);
  csrc[rowstart[dst] + pos] = src << 10;
}

// counting sort of nodes by degree, DESCENDING (256 bins)
__global__ void dbin_hist(const int* __restrict__ deg, int* __restrict__ dhist) {
  int n = blockIdx.x * 256 + threadIdx.x;
  if (n >= NN) return;
  int b = deg[n]; if (b > 255) b = 255;
  atomicAdd(&dhist[b], 1);
}

__global__ void dbin_scan(const int* __restrict__ dhist, int* __restrict__ doff) {
  if (threadIdx.x == 0 && blockIdx.x == 0) {
    int run = 0;
    for (int b = 255; b >= 0; --b) { doff[b] = run; run += dhist[b]; }
  }
}

__global__ void dbin_scatter(const int* __restrict__ deg, const int* __restrict__ doff,
                             int* __restrict__ dcur, int* __restrict__ perm) {
  int n = blockIdx.x * 256 + threadIdx.x;
  if (n >= NN) return;
  int b = deg[n]; if (b > 255) b = 255;
  int pos = doff[b] + atomicAdd(&dcur[b], 1);
  perm[pos] = n;
}

// ---------------- MFMA helpers ----------------
__device__ __forceinline__ void gl_lds16(const void* g, void* l) {
  __builtin_amdgcn_global_load_lds((const unsigned int*)g, (unsigned int*)l, 16, 0, 0);
}

template <int K>
__device__ __forceinline__ void stage_tile(const unsigned short* gbase,
                                           unsigned char* lbase, int tid) {
  constexpr int CH = K / 8;
  constexpr int ISS = (128 * CH) / 256;
  int wave = tid >> 6;
#pragma unroll
  for (int p = 0; p < ISS; p++) {
    int slot = p * 256 + tid;
    int row = slot / CH, ch = slot % CH;
    const unsigned short* src = gbase + (size_t)row * K + ((ch ^ (row & 7)) * 8);
    unsigned char* ldst = lbase + (size_t)(p * 256 + wave * 64) * 16;
    gl_lds16(src, ldst);
  }
}

template <int K>
__device__ __forceinline__ bf16x8 read_frag(const unsigned char* lbase, int row, int kk, int lk) {
  int ch = (kk * 4 + lk) ^ (row & 7);
  return *(const bf16x8*)(lbase + (size_t)row * (K * 2) + ch * 16);
}

// ---------------- input-projection GEMM (128x128 tile, K=64) ----------------
__global__ __launch_bounds__(256) void mfma_gemm_in(
    const unsigned short* __restrict__ A, const unsigned short* __restrict__ BT,
    const float* __restrict__ bias, unsigned short* __restrict__ outb,
    float* __restrict__ outf) {
  __shared__ __align__(16) unsigned char LDS[34816];
  const int tid = threadIdx.x;
  const int lane = tid & 63, wave = tid >> 6;
  const int lm = lane & 15, lk = lane >> 4;
  const int wm = wave >> 1, wn = wave & 1;
  const int row0 = blockIdx.x * 128;
  unsigned char* aL = LDS;
  unsigned char* bL = LDS + 128 * 64 * 2;

  stage_tile<64>(A + (size_t)row0 * 64, aL, tid);
  stage_tile<64>(BT, bL, tid);
  __syncthreads();

  f32x4 acc[4][4] = {};
  bf16x8 af[4][2];
#pragma unroll
  for (int mf = 0; mf < 4; mf++)
#pragma unroll
    for (int kk = 0; kk < 2; kk++)
      af[mf][kk] = read_frag<64>(aL, wm * 64 + mf * 16 + lm, kk, lk);
#pragma unroll
  for (int nf = 0; nf < 4; nf++) {
    bf16x8 bf[2];
#pragma unroll
    for (int kk = 0; kk < 2; kk++)
      bf[kk] = read_frag<64>(bL, wn * 64 + nf * 16 + lm, kk, lk);
#pragma unroll
    for (int mf = 0; mf < 4; mf++)
#pragma unroll
      for (int kk = 0; kk < 2; kk++)
        acc[mf][nf] = __builtin_amdgcn_mfma_f32_16x16x32_bf16(af[mf][kk], bf[kk],
                                                              acc[mf][nf], 0, 0, 0);
  }
  __syncthreads();

  unsigned short* bb = (unsigned short*)LDS;
#pragma unroll
  for (int nf = 0; nf < 4; nf++) {
    int c = wn * 64 + nf * 16 + lm;
    float bv = bias[c];
#pragma unroll
    for (int mf = 0; mf < 4; mf++)
#pragma unroll
      for (int i = 0; i < 4; i++) {
        int row = wm * 64 + mf * 16 + lk * 4 + i;
        float o = acc[mf][nf][i] + bv;
        bb[row * 136 + c] = f2bf(o);
        int r = row0 + row;
        if (r < NN) outf[(size_t)r * HIDC + c] = o;
      }
  }
  __syncthreads();
#pragma unroll
  for (int p = 0; p < 8; p++) {
    int idx = p * 256 + tid;
    int row = idx >> 4, c = idx & 15;
    int gr = row0 + row;
    if (gr < NN) {
      uint4 v = *(const uint4*)(bb + row * 136 + c * 8);
      *(uint4*)(outb + (size_t)gr * HIDC + c * 8) = v;
    }
  }
}

// ---------------- layer GEMM: 64x64 tiles, 32KB LDS, 5 blocks/CU ----------------
__global__ __launch_bounds__(256, 5) void gemm64(
    const unsigned short* __restrict__ A, const unsigned short* __restrict__ BT,
    const float* __restrict__ bias, unsigned short* __restrict__ qb,
    unsigned char* __restrict__ kv8, float* __restrict__ skipb,
    int nbx, int nwg) {
  __shared__ __align__(16) unsigned char LDS[32768];
  const int tid = threadIdx.x;
  int orig = blockIdx.x;
  int qq = nwg >> 3, rr8 = nwg & 7;
  int xcd = orig & 7, slot = orig >> 3;
  int wg = (xcd < rr8 ? xcd * (qq + 1) : rr8 * (qq + 1) + (xcd - rr8) * qq) + slot;
  const int bx = wg % nbx, by = wg / nbx;

  const int lane = tid & 63, wave = tid >> 6;
  const int lm = lane & 15, lk = lane >> 4;
  const int wm = wave >> 1, wn = wave & 1;
  const int row0 = by * 64, col0 = bx * 64;
  unsigned char* aL = LDS;
  unsigned char* bL = LDS + 16384;

  {
    const unsigned short* gA = A + (size_t)row0 * 128;
    const unsigned short* gB = BT + (size_t)col0 * 128;
#pragma unroll
    for (int p = 0; p < 4; p++) {
      int sl = p * 256 + tid;
      int row = sl >> 4, ch = sl & 15;
      gl_lds16(gA + (size_t)row * 128 + ((ch ^ (row & 7)) * 8),
               aL + (size_t)(p * 256 + wave * 64) * 16);
    }
#pragma unroll
    for (int p = 0; p < 4; p++) {
      int sl = p * 256 + tid;
      int row = sl >> 4, ch = sl & 15;
      gl_lds16(gB + (size_t)row * 128 + ((ch ^ (row & 7)) * 8),
               bL + (size_t)(p * 256 + wave * 64) * 16);
    }
  }
  __syncthreads();

  f32x4 acc[2][2] = {};
  bf16x8 af[2][4], bf[2][4];
#pragma unroll
  for (int mf = 0; mf < 2; mf++)
#pragma unroll
    for (int kk = 0; kk < 4; kk++)
      af[mf][kk] = read_frag<128>(aL, wm * 32 + mf * 16 + lm, kk, lk);
#pragma unroll
  for (int nf = 0; nf < 2; nf++)
#pragma unroll
    for (int kk = 0; kk < 4; kk++)
      bf[nf][kk] = read_frag<128>(bL, wn * 32 + nf * 16 + lm, kk, lk);
#pragma unroll
  for (int nf = 0; nf < 2; nf++)
#pragma unroll
    for (int mf = 0; mf < 2; mf++)
#pragma unroll
      for (int kk = 0; kk < 4; kk++)
        acc[mf][nf] = __builtin_amdgcn_mfma_f32_16x16x32_bf16(af[mf][kk], bf[nf][kk],
                                                              acc[mf][nf], 0, 0, 0);
  __syncthreads();

  if (bx >= 24) {
    const int cbase = col0 - 1536;
#pragma unroll
    for (int nf = 0; nf < 2; nf++) {
      int c = wn * 32 + nf * 16 + lm;
      float bv = bias[col0 + c];
#pragma unroll
      for (int mf = 0; mf < 2; mf++)
#pragma unroll
        for (int i = 0; i < 4; i++) {
          int r = row0 + wm * 32 + mf * 16 + lk * 4 + i;
          if (r < NN) skipb[(size_t)r * HIDC + cbase + c] = acc[mf][nf][i] + bv;
        }
    }
  } else if (bx >= 8) {
    unsigned char* bb8 = LDS;
#pragma unroll
    for (int nf = 0; nf < 2; nf++) {
      int c = wn * 32 + nf * 16 + lm;
      float bv = bias[col0 + c];
#pragma unroll
      for (int mf = 0; mf < 2; mf++)
#pragma unroll
        for (int i = 0; i < 4; i++) {
          int row = wm * 32 + mf * 16 + lk * 4 + i;
          bb8[row * 80 + c] = f2fp8(acc[mf][nf][i] + bv);
        }
    }
    __syncthreads();
    const int kvcol0 = col0 - 512;
    {
      int row = tid >> 2, cw = tid & 3;
      int gr = row0 + row;
      if (gr < NN) {
        uint4 v = *(const uint4*)(bb8 + row * 80 + cw * 16);
        *(uint4*)(kv8 + (size_t)gr * 1024 + kvcol0 + cw * 16) = v;
      }
    }
  } else {
    unsigned short* bb = (unsigned short*)LDS;
#pragma unroll
    for (int nf = 0; nf < 2; nf++) {
      int c = wn * 32 + nf * 16 + lm;
      float bv = bias[col0 + c];
#pragma unroll
      for (int mf = 0; mf < 2; mf++)
#pragma unroll
        for (int i = 0; i < 4; i++) {
          int row = wm * 32 + mf * 16 + lk * 4 + i;
          bb[row * 80 + c] = f2bf(acc[mf][nf][i] + bv);
        }
    }
    __syncthreads();
#pragma unroll
    for (int p = 0; p < 2; p++) {
      int idx = p * 256 + tid;
      int row = idx >> 3, cw = idx & 7;
      int gr = row0 + row;
      if (gr < NN) {
        uint4 v = *(const uint4*)(bb + row * 80 + cw * 8);
        *(uint4*)(qb + (size_t)gr * 512 + col0 + cw * 8) = v;
      }
    }
  }
}

// ---------------- fused single-pass flash-style node kernel (fp8 k/v) ----------------
// degree-sorted perm: 4 equal-degree nodes per block, longest first
__global__ __launch_bounds__(256) void node_fused(
    const unsigned short* __restrict__ qb, const unsigned char* __restrict__ kv8,
    const float* __restrict__ skipb,
    const float* __restrict__ h, const int* __restrict__ rowstart,
    const int* __restrict__ csrc, const int* __restrict__ perm,
    const float* __restrict__ gamma, const float* __restrict__ beta,
    float* __restrict__ outp, unsigned short* __restrict__ hb_out) {
  int gid = blockIdx.x * 4 + (threadIdx.x >> 6);
  if (gid >= NN) return;
  int n = perm[gid];
  int lane = threadIdx.x & 63;
  int hh = lane >> 4, t = lane & 15;
  int j0 = rowstart[n], j1 = rowstart[n + 1];

  u16x8 q8 = *(const u16x8*)(qb + (size_t)n * 512 + hh * 128 + t * 8);
  float qf[8];
#pragma unroll
  for (int i = 0; i < 8; i++) qf[i] = bf2f(q8[i]);

  const unsigned char* kb = kv8 + hh * 128 + t * 8;        // + csrc byte offset
  const unsigned char* vb = kv8 + 512 + hh * 128 + t * 8;

  float m = -INFINITY, s = 0.f;
  float acc[8] = {0.f, 0.f, 0.f, 0.f, 0.f, 0.f, 0.f, 0.f};

  int j = j0;
  for (; j + 3 < j1; j += 4) {
    int s4[4];
#pragma unroll
    for (int e = 0; e < 4; e++) s4[e] = csrc[j + e];
    uint2 kk4[4], vv4[4];
#pragma unroll
    for (int e = 0; e < 4; e++) {
      kk4[e] = *(const uint2*)(kb + (size_t)s4[e]);
      vv4[e] = *(const uint2*)(vb + (size_t)s4[e]);
    }
    float lg4[4];
#pragma unroll
    for (int e = 0; e < 4; e++) {
      float kf[8];
      dec8(kk4[e], kf);
      float p = 0.f;
#pragma unroll
      for (int i = 0; i < 8; i++) p += qf[i] * kf[i];
      p += __shfl_xor(p, 1);
      p += __shfl_xor(p, 2);
      p += __shfl_xor(p, 4);
      p += __shfl_xor(p, 8);
      lg4[e] = p * 0.08838834764831845f;
    }
    float mx = fmaxf(fmaxf(lg4[0], lg4[1]), fmaxf(lg4[2], lg4[3]));
    if (mx > m) {
      float rr = __expf(m - mx);
      s *= rr;
#pragma unroll
      for (int i = 0; i < 8; i++) acc[i] *= rr;
      m = mx;
    }
#pragma unroll
    for (int e = 0; e < 4; e++) {
      float w = __expf(lg4[e] - m);
      s += w;
      float vf[8];
      dec8(vv4[e], vf);
#pragma unroll
      for (int i = 0; i < 8; i++) acc[i] += w * vf[i];
    }
  }
  for (; j < j1; ++j) {
    int sA = csrc[j];
    uint2 kA = *(const uint2*)(kb + (size_t)sA);
    uint2 vA = *(const uint2*)(vb + (size_t)sA);
    float kfA[8], vfA[8];
    dec8(kA, kfA); dec8(vA, vfA);
    float pA = 0.f;
#pragma unroll
    for (int i = 0; i < 8; i++) pA += qf[i] * kfA[i];
    pA += __shfl_xor(pA, 1);
    pA += __shfl_xor(pA, 2);
    pA += __shfl_xor(pA, 4);
    pA += __shfl_xor(pA, 8);
    float lgA = pA * 0.08838834764831845f;
    if (lgA > m) {
      float rr = __expf(m - lgA);
      s *= rr;
#pragma unroll
      for (int i = 0; i < 8; i++) acc[i] *= rr;
      m = lgA;
    }
    float wA = __expf(lgA - m);
    s += wA;
#pragma unroll
    for (int i = 0; i < 8; i++) acc[i] += wA * vfA[i];
  }

  float rsel = 0.25f / (s + 1e-16f);
#pragma unroll
  for (int i = 0; i < 8; i++) {
    float a = acc[i] * rsel;
    a += __shfl_xor(a, 16);
    a += __shfl_xor(a, 32);
    acc[i] = a;
  }

  size_t hbase = (size_t)n * HIDC;
  float u[8];
  {
    float4 h0 = *(const float4*)(h + hbase + t * 8);
    float4 h1 = *(const float4*)(h + hbase + t * 8 + 4);
    float4 k0 = *(const float4*)(skipb + hbase + t * 8);
    float4 k1 = *(const float4*)(skipb + hbase + t * 8 + 4);
    u[0] = h0.x + acc[0] + k0.x; u[1] = h0.y + acc[1] + k0.y;
    u[2] = h0.z + acc[2] + k0.z; u[3] = h0.w + acc[3] + k0.w;
    u[4] = h1.x + acc[4] + k1.x; u[5] = h1.y + acc[5] + k1.y;
    u[6] = h1.z + acc[6] + k1.z; u[7] = h1.w + acc[7] + k1.w;
  }
  float su = 0.f;
#pragma unroll
  for (int i = 0; i < 8; i++) su += u[i];
#pragma unroll
  for (int d = 1; d < 16; d <<= 1) su += __shfl_xor(su, d);
  float mu = su * (1.f / 128.f);
  float vs = 0.f;
#pragma unroll
  for (int i = 0; i < 8; i++) { u[i] -= mu; vs += u[i] * u[i]; }
#pragma unroll
  for (int d = 1; d < 16; d <<= 1) vs += __shfl_xor(vs, d);
  float inv = rsqrtf(vs * (1.f / 128.f) + 1e-5f);
  if (hh == 0) {
    float4 g0 = *(const float4*)(gamma + t * 8);
    float4 g1 = *(const float4*)(gamma + t * 8 + 4);
    float4 b0 = *(const float4*)(beta + t * 8);
    float4 b1 = *(const float4*)(beta + t * 8 + 4);
    float o[8];
    o[0] = u[0] * inv * g0.x + b0.x; o[1] = u[1] * inv * g0.y + b0.y;
    o[2] = u[2] * inv * g0.z + b0.z; o[3] = u[3] * inv * g0.w + b0.w;
    o[4] = u[4] * inv * g1.x + b1.x; o[5] = u[5] * inv * g1.y + b1.y;
    o[6] = u[6] * inv * g1.z + b1.z; o[7] = u[7] * inv * g1.w + b1.w;
    *(float4*)(outp + hbase + t * 8)     = make_float4(o[0], o[1], o[2], o[3]);
    *(float4*)(outp + hbase + t * 8 + 4) = make_float4(o[4], o[5], o[6], o[7]);
    ushort4 c0 = make_ushort4(f2bf(o[0]), f2bf(o[1]), f2bf(o[2]), f2bf(o[3]));
    ushort4 c1 = make_ushort4(f2bf(o[4]), f2bf(o[5]), f2bf(o[6]), f2bf(o[7]));
    *(ushort4*)(hb_out + hbase + t * 8)     = c0;
    *(ushort4*)(hb_out + hbase + t * 8 + 4) = c1;
  }
}

// ---------------- workspace layout (float offsets, all 16B-aligned) ----------------
#define OFF_H      ((size_t)0)            // N*128 fp32
#define OFF_SKIP   ((size_t)2560000)      // N*128 fp32
#define OFF_QB     ((size_t)5120000)      // N*512 bf16
#define OFF_KV8    ((size_t)10240000)     // N*1024 fp8
#define OFF_HB     ((size_t)15360000)     // N*128 bf16
#define OFF_XB     ((size_t)16640000)     // N*64 bf16
#define OFF_WT     ((size_t)17280000)     // 3*1664*128 bf16
#define OFF_WINT   ((size_t)17599488)     // 128*64 bf16
#define OFF_BCAT   ((size_t)17603584)     // 3*1664 fp32
#define OFF_CSRC   ((size_t)17608576)     // E ints
#define OFF_ROW    ((size_t)17928576)     // N+1 ints
#define OFF_DEG    ((size_t)17948580)     // N ints
#define OFF_CUR    ((size_t)17968580)     // N ints
#define OFF_PERM   ((size_t)17988580)     // N ints
#define OFF_DHIST  ((size_t)18008580)     // 256 ints
#define OFF_DOFF   ((size_t)18008836)     // 256 ints
#define OFF_DCUR   ((size_t)18009092)     // 256 ints
// end ~18.01M floats ~= 72 MB

extern "C" void kernel_launch(void* const* d_in, const int* in_sizes, int n_in,
                              void* d_out, int out_size, void* d_ws, size_t ws_size,
                              hipStream_t stream) {
  const float* x    = (const float*)d_in[0];
  const int*   ei   = (const int*)d_in[1];
  const float* Win  = (const float*)d_in[2];
  const float* bin_ = (const float*)d_in[3];
  const float* Wq   = (const float*)d_in[4];
  const float* bq   = (const float*)d_in[5];
  const float* Wk   = (const float*)d_in[6];
  const float* bk   = (const float*)d_in[7];
  const float* Wv   = (const float*)d_in[8];
  const float* bv   = (const float*)d_in[9];
  const float* Wsk  = (const float*)d_in[10];
  const float* bsk  = (const float*)d_in[11];
  const float* lng  = (const float*)d_in[12];
  const float* lnb  = (const float*)d_in[13];
  float* out = (float*)d_out;
  float* ws = (float*)d_ws;

  float* h     = ws + OFF_H;
  float* skipb = ws + OFF_SKIP;
  unsigned short* qb   = (unsigned short*)(ws + OFF_QB);
  unsigned char*  kv8  = (unsigned char*)(ws + OFF_KV8);
  unsigned short* hb   = (unsigned short*)(ws + OFF_HB);
  unsigned short* xb   = (unsigned short*)(ws + OFF_XB);
  unsigned short* wT   = (unsigned short*)(ws + OFF_WT);
  unsigned short* winT = (unsigned short*)(ws + OFF_WINT);
  float* bcat  = ws + OFF_BCAT;
  int* csrc     = (int*)(ws + OFF_CSRC);
  int* rowstart = (int*)(ws + OFF_ROW);
  int* deg      = (int*)(ws + OFF_DEG);
  int* cur      = (int*)(ws + OFF_CUR);
  int* perm     = (int*)(ws + OFF_PERM);
  int* dhist    = (int*)(ws + OFF_DHIST);
  int* doff     = (int*)(ws + OFF_DOFF);
  int* dcur     = (int*)(ws + OFF_DCUR);

  // ---- CSR build + degree sort + weight prep ----
  hipMemsetAsync(deg, 0, NN * sizeof(int), stream);
  hipMemsetAsync(cur, 0, NN * sizeof(int), stream);
  hipMemsetAsync(dhist, 0, 256 * sizeof(int), stream);
  hipMemsetAsync(dcur, 0, 256 * sizeof(int), stream);
  deg_hist<<<(EE + 255) / 256, 256, 0, stream>>>(ei, deg);
  scan_deg<<<1, 1024, 0, stream>>>(deg, rowstart);
  csr_scatter<<<(EE + 255) / 256, 256, 0, stream>>>(ei, rowstart, cur, csrc);
  dbin_hist<<<(NN + 255) / 256, 256, 0, stream>>>(deg, dhist);
  dbin_scan<<<1, 64, 0, stream>>>(dhist, doff);
  dbin_scatter<<<(NN + 255) / 256, 256, 0, stream>>>(deg, doff, dcur, perm);

  conv_x<<<(NN * DIN / 4 + 255) / 256, 256, 0, stream>>>(x, xb);
  build_winT<<<(HIDC * DIN + 255) / 256, 256, 0, stream>>>(Win, winT);
  build_wcatT_all<<<(NL * NCOLS * HIDC + 255) / 256, 256, 0, stream>>>(
      Wq, Wk, Wv, Wsk, wT);
  build_bcat_all<<<(NL * NCOLS + 255) / 256, 256, 0, stream>>>(bq, bk, bv, bsk, bcat);

  // ---- input projection via MFMA (K=64): h fp32 + hb bf16 ----
  mfma_gemm_in<<<(NN + 127) / 128, 256, 0, stream>>>(xb, winT, bin_, hb, h);

  const int nbx = NCOLS / 64;            // 26
  const int nby = (NN + 63) / 64;        // 313
  const int nwg = nbx * nby;             // 8138

  for (int l = 0; l < NL; ++l) {
    gemm64<<<nwg, 256, 0, stream>>>(hb, wT + (size_t)l * NCOLS * HIDC,
                                    bcat + (size_t)l * NCOLS, qb, kv8, skipb,
                                    nbx, nwg);

    float* dst = (l == NL - 1) ? out : h;
    node_fused<<<(NN + 3) / 4, 256, 0, stream>>>(
        qb, kv8, skipb, h, rowstart, csrc, perm,
        lng + (size_t)l * 128, lnb + (size_t)l * 128, dst, hb);
  }
  (void)in_sizes; (void)n_in; (void)out_size; (void)ws_size;
}

// Round 10
// 320.800 us; speedup vs baseline: 1.3614x; 1.3614x over previous
//
#include <hip/hip_runtime.h>
#include <hip/hip_bf16.h>
#include <math.h>

#define NN 20000
#define EE 320000
#define DIN 64
#define HIDC 128
#define NCOLS 1664   // 512 q | 1024 kv(fp8) | 128 skip
#define NL 3
// logit scale pre-multiplied by log2(e): exp2f(lg2) == expf(p/sqrt(128))
#define LG2SCALE 0.12751659601518297f

typedef __attribute__((ext_vector_type(8))) short bf16x8;
typedef __attribute__((ext_vector_type(8))) unsigned short u16x8;
typedef __attribute__((ext_vector_type(4))) float f32x4;

__device__ __forceinline__ float bf2f(unsigned short u) {
  union { unsigned i; float f; } v; v.i = ((unsigned)u) << 16; return v.f;
}
__device__ __forceinline__ unsigned short f2bf(float f) {
  __hip_bfloat16 b = __float2bfloat16(f);
  return *(unsigned short*)&b;
}

// ---- fp8 e4m3fn (OCP) encode/decode, HW cvt when available ----
__device__ __forceinline__ unsigned char f2fp8(float f) {
#if __has_builtin(__builtin_amdgcn_cvt_pk_fp8_f32)
  return (unsigned char)(__builtin_amdgcn_cvt_pk_fp8_f32(f, f, 0, 0) & 0xFF);
#else
  unsigned b = __float_as_uint(f);
  unsigned s = (b >> 24) & 0x80u;
  float a = fabsf(f);
  if (a < 0.015625f) return (unsigned char)s;
  unsigned mag = __float_as_uint(fminf(a, 448.f));
  mag += 0x7FFFFu + ((mag >> 20) & 1u);
  unsigned code = (mag >> 20) - (120u << 3);
  if (code > 0x7Eu) code = 0x7Eu;
  return (unsigned char)(s | code);
#endif
}

__device__ __forceinline__ float fp82f(unsigned b) {
  unsigned x = ((b & 0x80u) << 24) | ((b & 0x7fu) << 20);
  return __uint_as_float(x) * 0x1p+120f;
}

__device__ __forceinline__ void dec8(uint2 u, float* f) {
#if __has_builtin(__builtin_amdgcn_cvt_pk_f32_fp8)
  {
    auto p0 = __builtin_amdgcn_cvt_pk_f32_fp8(u.x, 0);
    auto p1 = __builtin_amdgcn_cvt_pk_f32_fp8(u.x, 1);
    auto p2 = __builtin_amdgcn_cvt_pk_f32_fp8(u.y, 0);
    auto p3 = __builtin_amdgcn_cvt_pk_f32_fp8(u.y, 1);
    f[0] = p0[0]; f[1] = p0[1]; f[2] = p1[0]; f[3] = p1[1];
    f[4] = p2[0]; f[5] = p2[1]; f[6] = p3[0]; f[7] = p3[1];
  }
#else
#pragma unroll
  for (int i = 0; i < 4; i++) f[i] = fp82f((u.x >> (8 * i)) & 0xFFu);
#pragma unroll
  for (int i = 0; i < 4; i++) f[4 + i] = fp82f((u.y >> (8 * i)) & 0xFFu);
#endif
}

// ---------------- weight/bias/input prep (all layers at once) ----------------
__global__ void build_wcatT_all(const float* __restrict__ Wq, const float* __restrict__ Wk,
                                const float* __restrict__ Wv, const float* __restrict__ Wsk,
                                unsigned short* __restrict__ wT) {
  int idx = blockIdx.x * 256 + threadIdx.x;
  if (idx >= NL * NCOLS * HIDC) return;
  int l = idx / (NCOLS * HIDC);
  int rem = idx - l * (NCOLS * HIDC);
  int n = rem >> 7, k = rem & 127;
  float v;
  if (n < 512)       v = Wq[(size_t)l * HIDC * 512 + (size_t)k * 512 + n];
  else if (n < 1024) v = Wk[(size_t)l * HIDC * 512 + (size_t)k * 512 + (n - 512)];
  else if (n < 1536) v = Wv[(size_t)l * HIDC * 512 + (size_t)k * 512 + (n - 1024)];
  else               v = Wsk[(size_t)l * HIDC * HIDC + (size_t)k * 128 + (n - 1536)];
  wT[idx] = f2bf(v);
}

__global__ void build_bcat_all(const float* __restrict__ bq, const float* __restrict__ bk,
                               const float* __restrict__ bv, const float* __restrict__ bsk,
                               float* __restrict__ bcat) {
  int idx = blockIdx.x * 256 + threadIdx.x;
  if (idx >= NL * NCOLS) return;
  int l = idx / NCOLS, m = idx - l * NCOLS;
  float v;
  if (m < 512)       v = bq[l * 512 + m];
  else if (m < 1024) v = bk[l * 512 + (m - 512)];
  else if (m < 1536) v = bv[l * 512 + (m - 1024)];
  else               v = bsk[l * 128 + (m - 1536)];
  bcat[idx] = v;
}

__global__ void build_winT(const float* __restrict__ Win, unsigned short* __restrict__ winT) {
  int idx = blockIdx.x * 256 + threadIdx.x;
  if (idx >= HIDC * DIN) return;
  int c = idx >> 6, k = idx & 63;
  winT[idx] = f2bf(Win[(size_t)k * HIDC + c]);
}

__global__ void conv_x(const float* __restrict__ x, unsigned short* __restrict__ xb) {
  int i = blockIdx.x * 256 + threadIdx.x;
  if (i * 4 >= NN * DIN) return;
  float4 v = *(const float4*)(x + (size_t)i * 4);
  ushort4 o = make_ushort4(f2bf(v.x), f2bf(v.y), f2bf(v.z), f2bf(v.w));
  *(ushort4*)(xb + (size_t)i * 4) = o;
}

// ---------------- CSR build ----------------
__global__ void deg_hist(const int* __restrict__ ei, int* __restrict__ deg) {
  int e = blockIdx.x * 256 + threadIdx.x;
  if (e >= EE) return;
  atomicAdd(&deg[ei[EE + e]], 1);
}

__global__ __launch_bounds__(1024) void scan_deg(const int* __restrict__ deg,
                                                 int* __restrict__ rowstart) {
  __shared__ int part[1024];
  int t = threadIdx.x;
  int base = t * 20;
  int local[20];
  int s = 0;
#pragma unroll
  for (int i = 0; i < 20; i++) {
    int idx = base + i;
    int d = (idx < NN) ? deg[idx] : 0;
    local[i] = d;
    s += d;
  }
  part[t] = s;
  __syncthreads();
  for (int d = 1; d < 1024; d <<= 1) {
    int v = (t >= d) ? part[t - d] : 0;
    __syncthreads();
    part[t] += v;
    __syncthreads();
  }
  int run = part[t] - s;
#pragma unroll
  for (int i = 0; i < 20; i++) {
    int idx = base + i;
    if (idx < NN) rowstart[idx] = run;
    run += local[i];
  }
  if (t == 1023) rowstart[NN] = part[1023];
}

// CSR entries = byte offsets into kv8 (src * 1024)
__global__ void csr_scatter(const int* __restrict__ ei, const int* __restrict__ rowstart,
                            int* __restrict__ cur, int* __restrict__ csrc) {
  int e = blockIdx.x * 256 + threadIdx.x;
  if (e >= EE) return;
  int src = ei[e], dst = ei[EE + e];
  int pos = atomicAdd(&cur[dst], 1);
  csrc[rowstart[dst] + pos] = src << 10;
}

// ---------------- MFMA helpers ----------------
__device__ __forceinline__ void gl_lds16(const void* g, void* l) {
  __builtin_amdgcn_global_load_lds((const unsigned int*)g, (unsigned int*)l, 16, 0, 0);
}

template <int K>
__device__ __forceinline__ void stage_tile(const unsigned short* gbase,
                                           unsigned char* lbase, int tid) {
  constexpr int CH = K / 8;
  constexpr int ISS = (128 * CH) / 256;
  int wave = tid >> 6;
#pragma unroll
  for (int p = 0; p < ISS; p++) {
    int slot = p * 256 + tid;
    int row = slot / CH, ch = slot % CH;
    const unsigned short* src = gbase + (size_t)row * K + ((ch ^ (row & 7)) * 8);
    unsigned char* ldst = lbase + (size_t)(p * 256 + wave * 64) * 16;
    gl_lds16(src, ldst);
  }
}

template <int K>
__device__ __forceinline__ bf16x8 read_frag(const unsigned char* lbase, int row, int kk, int lk) {
  int ch = (kk * 4 + lk) ^ (row & 7);
  return *(const bf16x8*)(lbase + (size_t)row * (K * 2) + ch * 16);
}

// ---------------- input-projection GEMM (128x128 tile, K=64) ----------------
__global__ __launch_bounds__(256) void mfma_gemm_in(
    const unsigned short* __restrict__ A, const unsigned short* __restrict__ BT,
    const float* __restrict__ bias, unsigned short* __restrict__ outb,
    float* __restrict__ outf) {
  __shared__ __align__(16) unsigned char LDS[34816];
  const int tid = threadIdx.x;
  const int lane = tid & 63, wave = tid >> 6;
  const int lm = lane & 15, lk = lane >> 4;
  const int wm = wave >> 1, wn = wave & 1;
  const int row0 = blockIdx.x * 128;
  unsigned char* aL = LDS;
  unsigned char* bL = LDS + 128 * 64 * 2;

  stage_tile<64>(A + (size_t)row0 * 64, aL, tid);
  stage_tile<64>(BT, bL, tid);
  __syncthreads();

  f32x4 acc[4][4] = {};
  bf16x8 af[4][2];
#pragma unroll
  for (int mf = 0; mf < 4; mf++)
#pragma unroll
    for (int kk = 0; kk < 2; kk++)
      af[mf][kk] = read_frag<64>(aL, wm * 64 + mf * 16 + lm, kk, lk);
#pragma unroll
  for (int nf = 0; nf < 4; nf++) {
    bf16x8 bf[2];
#pragma unroll
    for (int kk = 0; kk < 2; kk++)
      bf[kk] = read_frag<64>(bL, wn * 64 + nf * 16 + lm, kk, lk);
#pragma unroll
    for (int mf = 0; mf < 4; mf++)
#pragma unroll
      for (int kk = 0; kk < 2; kk++)
        acc[mf][nf] = __builtin_amdgcn_mfma_f32_16x16x32_bf16(af[mf][kk], bf[kk],
                                                              acc[mf][nf], 0, 0, 0);
  }
  __syncthreads();

  unsigned short* bb = (unsigned short*)LDS;
#pragma unroll
  for (int nf = 0; nf < 4; nf++) {
    int c = wn * 64 + nf * 16 + lm;
    float bv = bias[c];
#pragma unroll
    for (int mf = 0; mf < 4; mf++)
#pragma unroll
      for (int i = 0; i < 4; i++) {
        int row = wm * 64 + mf * 16 + lk * 4 + i;
        float o = acc[mf][nf][i] + bv;
        bb[row * 136 + c] = f2bf(o);
        int r = row0 + row;
        if (r < NN) outf[(size_t)r * HIDC + c] = o;
      }
  }
  __syncthreads();
#pragma unroll
  for (int p = 0; p < 8; p++) {
    int idx = p * 256 + tid;
    int row = idx >> 4, c = idx & 15;
    int gr = row0 + row;
    if (gr < NN) {
      uint4 v = *(const uint4*)(bb + row * 136 + c * 8);
      *(uint4*)(outb + (size_t)gr * HIDC + c * 8) = v;
    }
  }
}

// ---------------- layer GEMM: 64x64 tiles, 32KB LDS, 5 blocks/CU ----------------
__global__ __launch_bounds__(256, 5) void gemm64(
    const unsigned short* __restrict__ A, const unsigned short* __restrict__ BT,
    const float* __restrict__ bias, unsigned short* __restrict__ qb,
    unsigned char* __restrict__ kv8, float* __restrict__ skipb,
    int nbx, int nwg) {
  __shared__ __align__(16) unsigned char LDS[32768];
  const int tid = threadIdx.x;
  int orig = blockIdx.x;
  int qq = nwg >> 3, rr8 = nwg & 7;
  int xcd = orig & 7, slot = orig >> 3;
  int wg = (xcd < rr8 ? xcd * (qq + 1) : rr8 * (qq + 1) + (xcd - rr8) * qq) + slot;
  const int bx = wg % nbx, by = wg / nbx;

  const int lane = tid & 63, wave = tid >> 6;
  const int lm = lane & 15, lk = lane >> 4;
  const int wm = wave >> 1, wn = wave & 1;
  const int row0 = by * 64, col0 = bx * 64;
  unsigned char* aL = LDS;
  unsigned char* bL = LDS + 16384;

  {
    const unsigned short* gA = A + (size_t)row0 * 128;
    const unsigned short* gB = BT + (size_t)col0 * 128;
#pragma unroll
    for (int p = 0; p < 4; p++) {
      int sl = p * 256 + tid;
      int row = sl >> 4, ch = sl & 15;
      gl_lds16(gA + (size_t)row * 128 + ((ch ^ (row & 7)) * 8),
               aL + (size_t)(p * 256 + wave * 64) * 16);
    }
#pragma unroll
    for (int p = 0; p < 4; p++) {
      int sl = p * 256 + tid;
      int row = sl >> 4, ch = sl & 15;
      gl_lds16(gB + (size_t)row * 128 + ((ch ^ (row & 7)) * 8),
               bL + (size_t)(p * 256 + wave * 64) * 16);
    }
  }
  __syncthreads();

  f32x4 acc[2][2] = {};
  bf16x8 af[2][4], bf[2][4];
#pragma unroll
  for (int mf = 0; mf < 2; mf++)
#pragma unroll
    for (int kk = 0; kk < 4; kk++)
      af[mf][kk] = read_frag<128>(aL, wm * 32 + mf * 16 + lm, kk, lk);
#pragma unroll
  for (int nf = 0; nf < 2; nf++)
#pragma unroll
    for (int kk = 0; kk < 4; kk++)
      bf[nf][kk] = read_frag<128>(bL, wn * 32 + nf * 16 + lm, kk, lk);
#pragma unroll
  for (int nf = 0; nf < 2; nf++)
#pragma unroll
    for (int mf = 0; mf < 2; mf++)
#pragma unroll
      for (int kk = 0; kk < 4; kk++)
        acc[mf][nf] = __builtin_amdgcn_mfma_f32_16x16x32_bf16(af[mf][kk], bf[nf][kk],
                                                              acc[mf][nf], 0, 0, 0);
  __syncthreads();

  if (bx >= 24) {
    const int cbase = col0 - 1536;
#pragma unroll
    for (int nf = 0; nf < 2; nf++) {
      int c = wn * 32 + nf * 16 + lm;
      float bv = bias[col0 + c];
#pragma unroll
      for (int mf = 0; mf < 2; mf++)
#pragma unroll
        for (int i = 0; i < 4; i++) {
          int r = row0 + wm * 32 + mf * 16 + lk * 4 + i;
          if (r < NN) skipb[(size_t)r * HIDC + cbase + c] = acc[mf][nf][i] + bv;
        }
    }
  } else if (bx >= 8) {
    unsigned char* bb8 = LDS;
#pragma unroll
    for (int nf = 0; nf < 2; nf++) {
      int c = wn * 32 + nf * 16 + lm;
      float bv = bias[col0 + c];
#pragma unroll
      for (int mf = 0; mf < 2; mf++)
#pragma unroll
        for (int i = 0; i < 4; i++) {
          int row = wm * 32 + mf * 16 + lk * 4 + i;
          bb8[row * 80 + c] = f2fp8(acc[mf][nf][i] + bv);
        }
    }
    __syncthreads();
    const int kvcol0 = col0 - 512;
    {
      int row = tid >> 2, cw = tid & 3;
      int gr = row0 + row;
      if (gr < NN) {
        uint4 v = *(const uint4*)(bb8 + row * 80 + cw * 16);
        *(uint4*)(kv8 + (size_t)gr * 1024 + kvcol0 + cw * 16) = v;
      }
    }
  } else {
    unsigned short* bb = (unsigned short*)LDS;
#pragma unroll
    for (int nf = 0; nf < 2; nf++) {
      int c = wn * 32 + nf * 16 + lm;
      float bv = bias[col0 + c];
#pragma unroll
      for (int mf = 0; mf < 2; mf++)
#pragma unroll
        for (int i = 0; i < 4; i++) {
          int row = wm * 32 + mf * 16 + lk * 4 + i;
          bb[row * 80 + c] = f2bf(acc[mf][nf][i] + bv);
        }
    }
    __syncthreads();
#pragma unroll
    for (int p = 0; p < 2; p++) {
      int idx = p * 256 + tid;
      int row = idx >> 3, cw = idx & 7;
      int gr = row0 + row;
      if (gr < NN) {
        uint4 v = *(const uint4*)(bb + row * 80 + cw * 8);
        *(uint4*)(qb + (size_t)gr * 512 + col0 + cw * 8) = v;
      }
    }
  }
}

// ---------------- fused single-pass flash-style node kernel (fp8 k/v) ----------------
// 8-edge deep unroll: 16 gathers in flight before any use (T14 issue-early)
__global__ __launch_bounds__(256) void node_fused(
    const unsigned short* __restrict__ qb, const unsigned char* __restrict__ kv8,
    const float* __restrict__ skipb,
    const float* __restrict__ h, const int* __restrict__ rowstart,
    const int* __restrict__ csrc,
    const float* __restrict__ gamma, const float* __restrict__ beta,
    float* __restrict__ outp, unsigned short* __restrict__ hb_out) {
  int n = blockIdx.x * 4 + (threadIdx.x >> 6);
  if (n >= NN) return;
  int lane = threadIdx.x & 63;
  int hh = lane >> 4, t = lane & 15;
  int j0 = rowstart[n], j1 = rowstart[n + 1];

  u16x8 q8 = *(const u16x8*)(qb + (size_t)n * 512 + hh * 128 + t * 8);
  float qf[8];
#pragma unroll
  for (int i = 0; i < 8; i++) qf[i] = bf2f(q8[i]);

  const unsigned char* kb = kv8 + hh * 128 + t * 8;        // + csrc byte offset
  const unsigned char* vb = kv8 + 512 + hh * 128 + t * 8;

  float m = -INFINITY, s = 0.f;
  float acc[8] = {0.f, 0.f, 0.f, 0.f, 0.f, 0.f, 0.f, 0.f};

  int j = j0;
  // 8-edge unrolled main loop: all 16 k/v gathers issued before any use
  for (; j + 7 < j1; j += 8) {
    int s8[8];
#pragma unroll
    for (int e = 0; e < 8; e++) s8[e] = csrc[j + e];
    uint2 kk8[8], vv8[8];
#pragma unroll
    for (int e = 0; e < 8; e++) {
      kk8[e] = *(const uint2*)(kb + (size_t)s8[e]);
      vv8[e] = *(const uint2*)(vb + (size_t)s8[e]);
    }
    float lg8[8];
#pragma unroll
    for (int e = 0; e < 8; e++) {
      float kf[8];
      dec8(kk8[e], kf);
      float p = 0.f;
#pragma unroll
      for (int i = 0; i < 8; i++) p += qf[i] * kf[i];
      p += __shfl_xor(p, 1);
      p += __shfl_xor(p, 2);
      p += __shfl_xor(p, 4);
      p += __shfl_xor(p, 8);
      lg8[e] = p * LG2SCALE;
    }
    float mx = lg8[0];
#pragma unroll
    for (int e = 1; e < 8; e++) mx = fmaxf(mx, lg8[e]);
    if (mx > m) {
      float rr = exp2f(m - mx);  // exp2(-inf)=0 bootstraps first group
      s *= rr;
#pragma unroll
      for (int i = 0; i < 8; i++) acc[i] *= rr;
      m = mx;
    }
#pragma unroll
    for (int e = 0; e < 8; e++) {
      float w = exp2f(lg8[e] - m);
      s += w;
      float vf[8];
      dec8(vv8[e], vf);
#pragma unroll
      for (int i = 0; i < 8; i++) acc[i] += w * vf[i];
    }
  }
  // 4-edge group
  for (; j + 3 < j1; j += 4) {
    int s4[4];
#pragma unroll
    for (int e = 0; e < 4; e++) s4[e] = csrc[j + e];
    uint2 kk4[4], vv4[4];
#pragma unroll
    for (int e = 0; e < 4; e++) {
      kk4[e] = *(const uint2*)(kb + (size_t)s4[e]);
      vv4[e] = *(const uint2*)(vb + (size_t)s4[e]);
    }
    float lg4[4];
#pragma unroll
    for (int e = 0; e < 4; e++) {
      float kf[8];
      dec8(kk4[e], kf);
      float p = 0.f;
#pragma unroll
      for (int i = 0; i < 8; i++) p += qf[i] * kf[i];
      p += __shfl_xor(p, 1);
      p += __shfl_xor(p, 2);
      p += __shfl_xor(p, 4);
      p += __shfl_xor(p, 8);
      lg4[e] = p * LG2SCALE;
    }
    float mx = fmaxf(fmaxf(lg4[0], lg4[1]), fmaxf(lg4[2], lg4[3]));
    if (mx > m) {
      float rr = exp2f(m - mx);
      s *= rr;
#pragma unroll
      for (int i = 0; i < 8; i++) acc[i] *= rr;
      m = mx;
    }
#pragma unroll
    for (int e = 0; e < 4; e++) {
      float w = exp2f(lg4[e] - m);
      s += w;
      float vf[8];
      dec8(vv4[e], vf);
#pragma unroll
      for (int i = 0; i < 8; i++) acc[i] += w * vf[i];
    }
  }
  // remainder singles
  for (; j < j1; ++j) {
    int sA = csrc[j];
    uint2 kA = *(const uint2*)(kb + (size_t)sA);
    uint2 vA = *(const uint2*)(vb + (size_t)sA);
    float kfA[8], vfA[8];
    dec8(kA, kfA); dec8(vA, vfA);
    float pA = 0.f;
#pragma unroll
    for (int i = 0; i < 8; i++) pA += qf[i] * kfA[i];
    pA += __shfl_xor(pA, 1);
    pA += __shfl_xor(pA, 2);
    pA += __shfl_xor(pA, 4);
    pA += __shfl_xor(pA, 8);
    float lgA = pA * LG2SCALE;
    if (lgA > m) {
      float rr = exp2f(m - lgA);
      s *= rr;
#pragma unroll
      for (int i = 0; i < 8; i++) acc[i] *= rr;
      m = lgA;
    }
    float wA = exp2f(lgA - m);
    s += wA;
#pragma unroll
    for (int i = 0; i < 8; i++) acc[i] += wA * vfA[i];
  }

  float rsel = 0.25f / (s + 1e-16f);
#pragma unroll
  for (int i = 0; i < 8; i++) {
    float a = acc[i] * rsel;
    a += __shfl_xor(a, 16);
    a += __shfl_xor(a, 32);
    acc[i] = a;
  }

  size_t hbase = (size_t)n * HIDC;
  float u[8];
  {
    float4 h0 = *(const float4*)(h + hbase + t * 8);
    float4 h1 = *(const float4*)(h + hbase + t * 8 + 4);
    float4 k0 = *(const float4*)(skipb + hbase + t * 8);
    float4 k1 = *(const float4*)(skipb + hbase + t * 8 + 4);
    u[0] = h0.x + acc[0] + k0.x; u[1] = h0.y + acc[1] + k0.y;
    u[2] = h0.z + acc[2] + k0.z; u[3] = h0.w + acc[3] + k0.w;
    u[4] = h1.x + acc[4] + k1.x; u[5] = h1.y + acc[5] + k1.y;
    u[6] = h1.z + acc[6] + k1.z; u[7] = h1.w + acc[7] + k1.w;
  }
  float su = 0.f;
#pragma unroll
  for (int i = 0; i < 8; i++) su += u[i];
#pragma unroll
  for (int d = 1; d < 16; d <<= 1) su += __shfl_xor(su, d);
  float mu = su * (1.f / 128.f);
  float vs = 0.f;
#pragma unroll
  for (int i = 0; i < 8; i++) { u[i] -= mu; vs += u[i] * u[i]; }
#pragma unroll
  for (int d = 1; d < 16; d <<= 1) vs += __shfl_xor(vs, d);
  float inv = rsqrtf(vs * (1.f / 128.f) + 1e-5f);
  if (hh == 0) {
    float4 g0 = *(const float4*)(gamma + t * 8);
    float4 g1 = *(const float4*)(gamma + t * 8 + 4);
    float4 b0 = *(const float4*)(beta + t * 8);
    float4 b1 = *(const float4*)(beta + t * 8 + 4);
    float o[8];
    o[0] = u[0] * inv * g0.x + b0.x; o[1] = u[1] * inv * g0.y + b0.y;
    o[2] = u[2] * inv * g0.z + b0.z; o[3] = u[3] * inv * g0.w + b0.w;
    o[4] = u[4] * inv * g1.x + b1.x; o[5] = u[5] * inv * g1.y + b1.y;
    o[6] = u[6] * inv * g1.z + b1.z; o[7] = u[7] * inv * g1.w + b1.w;
    *(float4*)(outp + hbase + t * 8)     = make_float4(o[0], o[1], o[2], o[3]);
    *(float4*)(outp + hbase + t * 8 + 4) = make_float4(o[4], o[5], o[6], o[7]);
    ushort4 c0 = make_ushort4(f2bf(o[0]), f2bf(o[1]), f2bf(o[2]), f2bf(o[3]));
    ushort4 c1 = make_ushort4(f2bf(o[4]), f2bf(o[5]), f2bf(o[6]), f2bf(o[7]));
    *(ushort4*)(hb_out + hbase + t * 8)     = c0;
    *(ushort4*)(hb_out + hbase + t * 8 + 4) = c1;
  }
}

// ---------------- workspace layout (float offsets, all 16B-aligned) ----------------
#define OFF_H      ((size_t)0)            // N*128 fp32
#define OFF_SKIP   ((size_t)2560000)      // N*128 fp32
#define OFF_QB     ((size_t)5120000)      // N*512 bf16
#define OFF_KV8    ((size_t)10240000)     // N*1024 fp8
#define OFF_HB     ((size_t)15360000)     // N*128 bf16
#define OFF_XB     ((size_t)16640000)     // N*64 bf16
#define OFF_WT     ((size_t)17280000)     // 3*1664*128 bf16
#define OFF_WINT   ((size_t)17599488)     // 128*64 bf16
#define OFF_BCAT   ((size_t)17603584)     // 3*1664 fp32
#define OFF_CSRC   ((size_t)17608576)     // E ints
#define OFF_ROW    ((size_t)17928576)     // N+1 ints
#define OFF_DEG    ((size_t)17948580)     // N ints
#define OFF_CUR    ((size_t)17968580)     // N ints

extern "C" void kernel_launch(void* const* d_in, const int* in_sizes, int n_in,
                              void* d_out, int out_size, void* d_ws, size_t ws_size,
                              hipStream_t stream) {
  const float* x    = (const float*)d_in[0];
  const int*   ei   = (const int*)d_in[1];
  const float* Win  = (const float*)d_in[2];
  const float* bin_ = (const float*)d_in[3];
  const float* Wq   = (const float*)d_in[4];
  const float* bq   = (const float*)d_in[5];
  const float* Wk   = (const float*)d_in[6];
  const float* bk   = (const float*)d_in[7];
  const float* Wv   = (const float*)d_in[8];
  const float* bv   = (const float*)d_in[9];
  const float* Wsk  = (const float*)d_in[10];
  const float* bsk  = (const float*)d_in[11];
  const float* lng  = (const float*)d_in[12];
  const float* lnb  = (const float*)d_in[13];
  float* out = (float*)d_out;
  float* ws = (float*)d_ws;

  float* h     = ws + OFF_H;
  float* skipb = ws + OFF_SKIP;
  unsigned short* qb   = (unsigned short*)(ws + OFF_QB);
  unsigned char*  kv8  = (unsigned char*)(ws + OFF_KV8);
  unsigned short* hb   = (unsigned short*)(ws + OFF_HB);
  unsigned short* xb   = (unsigned short*)(ws + OFF_XB);
  unsigned short* wT   = (unsigned short*)(ws + OFF_WT);
  unsigned short* winT = (unsigned short*)(ws + OFF_WINT);
  float* bcat  = ws + OFF_BCAT;
  int* csrc     = (int*)(ws + OFF_CSRC);
  int* rowstart = (int*)(ws + OFF_ROW);
  int* deg      = (int*)(ws + OFF_DEG);
  int* cur      = (int*)(ws + OFF_CUR);

  // ---- CSR build + weight prep (front-loaded) ----
  hipMemsetAsync(deg, 0, NN * sizeof(int), stream);
  hipMemsetAsync(cur, 0, NN * sizeof(int), stream);
  deg_hist<<<(EE + 255) / 256, 256, 0, stream>>>(ei, deg);
  scan_deg<<<1, 1024, 0, stream>>>(deg, rowstart);
  csr_scatter<<<(EE + 255) / 256, 256, 0, stream>>>(ei, rowstart, cur, csrc);

  conv_x<<<(NN * DIN / 4 + 255) / 256, 256, 0, stream>>>(x, xb);
  build_winT<<<(HIDC * DIN + 255) / 256, 256, 0, stream>>>(Win, winT);
  build_wcatT_all<<<(NL * NCOLS * HIDC + 255) / 256, 256, 0, stream>>>(
      Wq, Wk, Wv, Wsk, wT);
  build_bcat_all<<<(NL * NCOLS + 255) / 256, 256, 0, stream>>>(bq, bk, bv, bsk, bcat);

  // ---- input projection via MFMA (K=64): h fp32 + hb bf16 ----
  mfma_gemm_in<<<(NN + 127) / 128, 256, 0, stream>>>(xb, winT, bin_, hb, h);

  const int nbx = NCOLS / 64;            // 26
  const int nby = (NN + 63) / 64;        // 313
  const int nwg = nbx * nby;             // 8138

  for (int l = 0; l < NL; ++l) {
    gemm64<<<nwg, 256, 0, stream>>>(hb, wT + (size_t)l * NCOLS * HIDC,
                                    bcat + (size_t)l * NCOLS, qb, kv8, skipb,
                                    nbx, nwg);

    float* dst = (l == NL - 1) ? out : h;
    node_fused<<<(NN + 3) / 4, 256, 0, stream>>>(
        qb, kv8, skipb, h, rowstart, csrc,
        lng + (size_t)l * 128, lnb + (size_t)l * 128, dst, hb);
  }
  (void)in_sizes; (void)n_in; (void)out_size; (void)ws_size;
}

// Round 11
// 312.664 us; speedup vs baseline: 1.3968x; 1.0260x over previous
//
#include <hip/hip_runtime.h>
#include <hip/hip_bf16.h>
#include <math.h>

#define NN 20000
#define EE 320000
#define DIN 64
#define HIDC 128
#define NCOLS 1664   // 512 q | 1024 kv(fp8, interleaved) | 128 skip
#define NL 3
// logit scale pre-multiplied by log2(e): exp2f(lg2) == expf(p/sqrt(128))
#define LG2SCALE 0.12751659601518297f

typedef __attribute__((ext_vector_type(8))) short bf16x8;
typedef __attribute__((ext_vector_type(8))) unsigned short u16x8;
typedef __attribute__((ext_vector_type(4))) float f32x4;

__device__ __forceinline__ float bf2f(unsigned short u) {
  union { unsigned i; float f; } v; v.i = ((unsigned)u) << 16; return v.f;
}
__device__ __forceinline__ unsigned short f2bf(float f) {
  __hip_bfloat16 b = __float2bfloat16(f);
  return *(unsigned short*)&b;
}

// ---- fp8 e4m3fn (OCP) encode/decode, HW cvt when available ----
__device__ __forceinline__ unsigned char f2fp8(float f) {
#if __has_builtin(__builtin_amdgcn_cvt_pk_fp8_f32)
  return (unsigned char)(__builtin_amdgcn_cvt_pk_fp8_f32(f, f, 0, 0) & 0xFF);
#else
  unsigned b = __float_as_uint(f);
  unsigned s = (b >> 24) & 0x80u;
  float a = fabsf(f);
  if (a < 0.015625f) return (unsigned char)s;
  unsigned mag = __float_as_uint(fminf(a, 448.f));
  mag += 0x7FFFFu + ((mag >> 20) & 1u);
  unsigned code = (mag >> 20) - (120u << 3);
  if (code > 0x7Eu) code = 0x7Eu;
  return (unsigned char)(s | code);
#endif
}

__device__ __forceinline__ float fp82f(unsigned b) {
  unsigned x = ((b & 0x80u) << 24) | ((b & 0x7fu) << 20);
  return __uint_as_float(x) * 0x1p+120f;
}

__device__ __forceinline__ void dec8(uint2 u, float* f) {
#if __has_builtin(__builtin_amdgcn_cvt_pk_f32_fp8)
  {
    auto p0 = __builtin_amdgcn_cvt_pk_f32_fp8(u.x, 0);
    auto p1 = __builtin_amdgcn_cvt_pk_f32_fp8(u.x, 1);
    auto p2 = __builtin_amdgcn_cvt_pk_f32_fp8(u.y, 0);
    auto p3 = __builtin_amdgcn_cvt_pk_f32_fp8(u.y, 1);
    f[0] = p0[0]; f[1] = p0[1]; f[2] = p1[0]; f[3] = p1[1];
    f[4] = p2[0]; f[5] = p2[1]; f[6] = p3[0]; f[7] = p3[1];
  }
#else
#pragma unroll
  for (int i = 0; i < 4; i++) f[i] = fp82f((u.x >> (8 * i)) & 0xFFu);
#pragma unroll
  for (int i = 0; i < 4; i++) f[4 + i] = fp82f((u.y >> (8 * i)) & 0xFFu);
#endif
}

// ---------------- weight/bias/input prep (all layers at once) ----------------
__global__ void build_wcatT_all(const float* __restrict__ Wq, const float* __restrict__ Wk,
                                const float* __restrict__ Wv, const float* __restrict__ Wsk,
                                unsigned short* __restrict__ wT) {
  int idx = blockIdx.x * 256 + threadIdx.x;
  if (idx >= NL * NCOLS * HIDC) return;
  int l = idx / (NCOLS * HIDC);
  int rem = idx - l * (NCOLS * HIDC);
  int n = rem >> 7, k = rem & 127;
  float v;
  if (n < 512)       v = Wq[(size_t)l * HIDC * 512 + (size_t)k * 512 + n];
  else if (n < 1024) v = Wk[(size_t)l * HIDC * 512 + (size_t)k * 512 + (n - 512)];
  else if (n < 1536) v = Wv[(size_t)l * HIDC * 512 + (size_t)k * 512 + (n - 1024)];
  else               v = Wsk[(size_t)l * HIDC * HIDC + (size_t)k * 128 + (n - 1536)];
  wT[idx] = f2bf(v);
}

__global__ void build_bcat_all(const float* __restrict__ bq, const float* __restrict__ bk,
                               const float* __restrict__ bv, const float* __restrict__ bsk,
                               float* __restrict__ bcat) {
  int idx = blockIdx.x * 256 + threadIdx.x;
  if (idx >= NL * NCOLS) return;
  int l = idx / NCOLS, m = idx - l * NCOLS;
  float v;
  if (m < 512)       v = bq[l * 512 + m];
  else if (m < 1024) v = bk[l * 512 + (m - 512)];
  else if (m < 1536) v = bv[l * 512 + (m - 1024)];
  else               v = bsk[l * 128 + (m - 1536)];
  bcat[idx] = v;
}

__global__ void build_winT(const float* __restrict__ Win, unsigned short* __restrict__ winT) {
  int idx = blockIdx.x * 256 + threadIdx.x;
  if (idx >= HIDC * DIN) return;
  int c = idx >> 6, k = idx & 63;
  winT[idx] = f2bf(Win[(size_t)k * HIDC + c]);
}

__global__ void conv_x(const float* __restrict__ x, unsigned short* __restrict__ xb) {
  int i = blockIdx.x * 256 + threadIdx.x;
  if (i * 4 >= NN * DIN) return;
  float4 v = *(const float4*)(x + (size_t)i * 4);
  ushort4 o = make_ushort4(f2bf(v.x), f2bf(v.y), f2bf(v.z), f2bf(v.w));
  *(ushort4*)(xb + (size_t)i * 4) = o;
}

// ---------------- CSR build ----------------
__global__ void deg_hist(const int* __restrict__ ei, int* __restrict__ deg) {
  int e = blockIdx.x * 256 + threadIdx.x;
  if (e >= EE) return;
  atomicAdd(&deg[ei[EE + e]], 1);
}

__global__ __launch_bounds__(1024) void scan_deg(const int* __restrict__ deg,
                                                 int* __restrict__ rowstart) {
  __shared__ int part[1024];
  int t = threadIdx.x;
  int base = t * 20;
  int local[20];
  int s = 0;
#pragma unroll
  for (int i = 0; i < 20; i++) {
    int idx = base + i;
    int d = (idx < NN) ? deg[idx] : 0;
    local[i] = d;
    s += d;
  }
  part[t] = s;
  __syncthreads();
  for (int d = 1; d < 1024; d <<= 1) {
    int v = (t >= d) ? part[t - d] : 0;
    __syncthreads();
    part[t] += v;
    __syncthreads();
  }
  int run = part[t] - s;
#pragma unroll
  for (int i = 0; i < 20; i++) {
    int idx = base + i;
    if (idx < NN) rowstart[idx] = run;
    run += local[i];
  }
  if (t == 1023) rowstart[NN] = part[1023];
}

// CSR entries = byte offsets into kv8 (src * 1024)
__global__ void csr_scatter(const int* __restrict__ ei, const int* __restrict__ rowstart,
                            int* __restrict__ cur, int* __restrict__ csrc) {
  int e = blockIdx.x * 256 + threadIdx.x;
  if (e >= EE) return;
  int src = ei[e], dst = ei[EE + e];
  int pos = atomicAdd(&cur[dst], 1);
  csrc[rowstart[dst] + pos] = src << 10;
}

// ---------------- MFMA helpers ----------------
__device__ __forceinline__ void gl_lds16(const void* g, void* l) {
  __builtin_amdgcn_global_load_lds((const unsigned int*)g, (unsigned int*)l, 16, 0, 0);
}

template <int K>
__device__ __forceinline__ void stage_tile(const unsigned short* gbase,
                                           unsigned char* lbase, int tid) {
  constexpr int CH = K / 8;
  constexpr int ISS = (128 * CH) / 256;
  int wave = tid >> 6;
#pragma unroll
  for (int p = 0; p < ISS; p++) {
    int slot = p * 256 + tid;
    int row = slot / CH, ch = slot % CH;
    const unsigned short* src = gbase + (size_t)row * K + ((ch ^ (row & 7)) * 8);
    unsigned char* ldst = lbase + (size_t)(p * 256 + wave * 64) * 16;
    gl_lds16(src, ldst);
  }
}

template <int K>
__device__ __forceinline__ bf16x8 read_frag(const unsigned char* lbase, int row, int kk, int lk) {
  int ch = (kk * 4 + lk) ^ (row & 7);
  return *(const bf16x8*)(lbase + (size_t)row * (K * 2) + ch * 16);
}

// ---------------- input-projection GEMM (128x128 tile, K=64) ----------------
__global__ __launch_bounds__(256) void mfma_gemm_in(
    const unsigned short* __restrict__ A, const unsigned short* __restrict__ BT,
    const float* __restrict__ bias, unsigned short* __restrict__ outb,
    float* __restrict__ outf) {
  __shared__ __align__(16) unsigned char LDS[34816];
  const int tid = threadIdx.x;
  const int lane = tid & 63, wave = tid >> 6;
  const int lm = lane & 15, lk = lane >> 4;
  const int wm = wave >> 1, wn = wave & 1;
  const int row0 = blockIdx.x * 128;
  unsigned char* aL = LDS;
  unsigned char* bL = LDS + 128 * 64 * 2;

  stage_tile<64>(A + (size_t)row0 * 64, aL, tid);
  stage_tile<64>(BT, bL, tid);
  __syncthreads();

  f32x4 acc[4][4] = {};
  bf16x8 af[4][2];
#pragma unroll
  for (int mf = 0; mf < 4; mf++)
#pragma unroll
    for (int kk = 0; kk < 2; kk++)
      af[mf][kk] = read_frag<64>(aL, wm * 64 + mf * 16 + lm, kk, lk);
#pragma unroll
  for (int nf = 0; nf < 4; nf++) {
    bf16x8 bf[2];
#pragma unroll
    for (int kk = 0; kk < 2; kk++)
      bf[kk] = read_frag<64>(bL, wn * 64 + nf * 16 + lm, kk, lk);
#pragma unroll
    for (int mf = 0; mf < 4; mf++)
#pragma unroll
      for (int kk = 0; kk < 2; kk++)
        acc[mf][nf] = __builtin_amdgcn_mfma_f32_16x16x32_bf16(af[mf][kk], bf[kk],
                                                              acc[mf][nf], 0, 0, 0);
  }
  __syncthreads();

  unsigned short* bb = (unsigned short*)LDS;
#pragma unroll
  for (int nf = 0; nf < 4; nf++) {
    int c = wn * 64 + nf * 16 + lm;
    float bv = bias[c];
#pragma unroll
    for (int mf = 0; mf < 4; mf++)
#pragma unroll
      for (int i = 0; i < 4; i++) {
        int row = wm * 64 + mf * 16 + lk * 4 + i;
        float o = acc[mf][nf][i] + bv;
        bb[row * 136 + c] = f2bf(o);
        int r = row0 + row;
        if (r < NN) outf[(size_t)r * HIDC + c] = o;
      }
  }
  __syncthreads();
#pragma unroll
  for (int p = 0; p < 8; p++) {
    int idx = p * 256 + tid;
    int row = idx >> 4, c = idx & 15;
    int gr = row0 + row;
    if (gr < NN) {
      uint4 v = *(const uint4*)(bb + row * 136 + c * 8);
      *(uint4*)(outb + (size_t)gr * HIDC + c * 8) = v;
    }
  }
}

// ---------------- layer GEMM: 64x64 tiles, 32KB LDS, 5 blocks/CU ----------------
// bx 0-7: q cols (bf16) | bx 8-23: kv PAIRED (32 k-cols + matching 32 v-cols,
//   interleaved fp8 output: cell [hh][t] = {k 8B | v 8B}) | bx 24-25: skip fp32
__global__ __launch_bounds__(256, 5) void gemm64(
    const unsigned short* __restrict__ A, const unsigned short* __restrict__ BT,
    const float* __restrict__ bias, unsigned short* __restrict__ qb,
    unsigned char* __restrict__ kv8, float* __restrict__ skipb,
    int nbx, int nwg) {
  __shared__ __align__(16) unsigned char LDS[32768];
  const int tid = threadIdx.x;
  int orig = blockIdx.x;
  int qq = nwg >> 3, rr8 = nwg & 7;
  int xcd = orig & 7, slot = orig >> 3;
  int wg = (xcd < rr8 ? xcd * (qq + 1) : rr8 * (qq + 1) + (xcd - rr8) * qq) + slot;
  const int bx = wg % nbx, by = wg / nbx;

  const int lane = tid & 63, wave = tid >> 6;
  const int lm = lane & 15, lk = lane >> 4;
  const int wm = wave >> 1, wn = wave & 1;
  const int row0 = by * 64, col0 = bx * 64;
  const int kvbase = (bx - 8) * 32;  // valid for kv blocks
  unsigned char* aL = LDS;
  unsigned char* bL = LDS + 16384;

  {
    const unsigned short* gA = A + (size_t)row0 * 128;
#pragma unroll
    for (int p = 0; p < 4; p++) {
      int sl = p * 256 + tid;
      int row = sl >> 4, ch = sl & 15;
      gl_lds16(gA + (size_t)row * 128 + ((ch ^ (row & 7)) * 8),
               aL + (size_t)(p * 256 + wave * 64) * 16);
    }
    if (bx >= 8 && bx < 24) {
      // paired B rows: 0..31 from k cols 512+base.., 32..63 from v cols 1024+base..
#pragma unroll
      for (int p = 0; p < 4; p++) {
        int sl = p * 256 + tid;
        int row = sl >> 4, ch = sl & 15;
        int grow = (row < 32) ? (512 + kvbase + row) : (1024 + kvbase + row - 32);
        gl_lds16(BT + (size_t)grow * 128 + ((ch ^ (row & 7)) * 8),
                 bL + (size_t)(p * 256 + wave * 64) * 16);
      }
    } else {
      const unsigned short* gB = BT + (size_t)col0 * 128;
#pragma unroll
      for (int p = 0; p < 4; p++) {
        int sl = p * 256 + tid;
        int row = sl >> 4, ch = sl & 15;
        gl_lds16(gB + (size_t)row * 128 + ((ch ^ (row & 7)) * 8),
                 bL + (size_t)(p * 256 + wave * 64) * 16);
      }
    }
  }
  __syncthreads();

  f32x4 acc[2][2] = {};
  bf16x8 af[2][4], bf[2][4];
#pragma unroll
  for (int mf = 0; mf < 2; mf++)
#pragma unroll
    for (int kk = 0; kk < 4; kk++)
      af[mf][kk] = read_frag<128>(aL, wm * 32 + mf * 16 + lm, kk, lk);
#pragma unroll
  for (int nf = 0; nf < 2; nf++)
#pragma unroll
    for (int kk = 0; kk < 4; kk++)
      bf[nf][kk] = read_frag<128>(bL, wn * 32 + nf * 16 + lm, kk, lk);
#pragma unroll
  for (int nf = 0; nf < 2; nf++)
#pragma unroll
    for (int mf = 0; mf < 2; mf++)
#pragma unroll
      for (int kk = 0; kk < 4; kk++)
        acc[mf][nf] = __builtin_amdgcn_mfma_f32_16x16x32_bf16(af[mf][kk], bf[nf][kk],
                                                              acc[mf][nf], 0, 0, 0);
  __syncthreads();

  if (bx >= 24) {
    const int cbase = col0 - 1536;
#pragma unroll
    for (int nf = 0; nf < 2; nf++) {
      int c = wn * 32 + nf * 16 + lm;
      float bv = bias[col0 + c];
#pragma unroll
      for (int mf = 0; mf < 2; mf++)
#pragma unroll
        for (int i = 0; i < 4; i++) {
          int r = row0 + wm * 32 + mf * 16 + lk * 4 + i;
          if (r < NN) skipb[(size_t)r * HIDC + cbase + c] = acc[mf][nf][i] + bv;
        }
    }
  } else if (bx >= 8) {
    // interleaved kv fp8 bounce: local 64B window per row ([64][80] bytes)
    unsigned char* bb8 = LDS;
#pragma unroll
    for (int nf = 0; nf < 2; nf++) {
      int c = wn * 32 + nf * 16 + lm;        // tile col: <32 = k, >=32 = v
      int jj = c & 31;
      float bv = bias[(c < 32) ? (512 + kvbase + jj) : (1024 + kvbase + jj)];
      int lc = ((jj >> 3) << 4) + ((c < 32) ? 0 : 8) + (jj & 7);
#pragma unroll
      for (int mf = 0; mf < 2; mf++)
#pragma unroll
        for (int i = 0; i < 4; i++) {
          int row = wm * 32 + mf * 16 + lk * 4 + i;
          bb8[row * 80 + lc] = f2fp8(acc[mf][nf][i] + bv);
        }
    }
    __syncthreads();
    // copy: 64 rows x 64B contiguous at kv8 + n*1024 + 2*kvbase
    {
      int row = tid >> 2, cw = tid & 3;
      int gr = row0 + row;
      if (gr < NN) {
        uint4 v = *(const uint4*)(bb8 + row * 80 + cw * 16);
        *(uint4*)(kv8 + (size_t)gr * 1024 + 2 * kvbase + cw * 16) = v;
      }
    }
  } else {
    unsigned short* bb = (unsigned short*)LDS;
#pragma unroll
    for (int nf = 0; nf < 2; nf++) {
      int c = wn * 32 + nf * 16 + lm;
      float bv = bias[col0 + c];
#pragma unroll
      for (int mf = 0; mf < 2; mf++)
#pragma unroll
        for (int i = 0; i < 4; i++) {
          int row = wm * 32 + mf * 16 + lk * 4 + i;
          bb[row * 80 + c] = f2bf(acc[mf][nf][i] + bv);
        }
    }
    __syncthreads();
#pragma unroll
    for (int p = 0; p < 2; p++) {
      int idx = p * 256 + tid;
      int row = idx >> 3, cw = idx & 7;
      int gr = row0 + row;
      if (gr < NN) {
        uint4 v = *(const uint4*)(bb + row * 80 + cw * 8);
        *(uint4*)(qb + (size_t)gr * 512 + col0 + cw * 8) = v;
      }
    }
  }
}

// ---------------- fused single-pass flash-style node kernel ----------------
// interleaved kv: one uint4 per edge per lane = k 8B + v 8B
__global__ __launch_bounds__(256) void node_fused(
    const unsigned short* __restrict__ qb, const unsigned char* __restrict__ kv8,
    const float* __restrict__ skipb,
    const float* __restrict__ h, const int* __restrict__ rowstart,
    const int* __restrict__ csrc,
    const float* __restrict__ gamma, const float* __restrict__ beta,
    float* __restrict__ outp, unsigned short* __restrict__ hb_out) {
  int n = blockIdx.x * 4 + (threadIdx.x >> 6);
  if (n >= NN) return;
  int lane = threadIdx.x & 63;
  int hh = lane >> 4, t = lane & 15;
  int j0 = rowstart[n], j1 = rowstart[n + 1];

  u16x8 q8 = *(const u16x8*)(qb + (size_t)n * 512 + hh * 128 + t * 8);
  float qf[8];
#pragma unroll
  for (int i = 0; i < 8; i++) qf[i] = bf2f(q8[i]);

  const unsigned char* kvp = kv8 + hh * 256 + t * 16;  // + csrc byte offset

  float m = -INFINITY, s = 0.f;
  float acc[8] = {0.f, 0.f, 0.f, 0.f, 0.f, 0.f, 0.f, 0.f};

  int j = j0;
  // 4-edge unrolled main loop: 4 x 16B gathers in flight before any use
  for (; j + 3 < j1; j += 4) {
    int s4[4];
#pragma unroll
    for (int e = 0; e < 4; e++) s4[e] = csrc[j + e];
    uint4 kv4[4];
#pragma unroll
    for (int e = 0; e < 4; e++) kv4[e] = *(const uint4*)(kvp + (size_t)s4[e]);
    float lg4[4];
#pragma unroll
    for (int e = 0; e < 4; e++) {
      float kf[8];
      dec8(make_uint2(kv4[e].x, kv4[e].y), kf);
      float p = 0.f;
#pragma unroll
      for (int i = 0; i < 8; i++) p += qf[i] * kf[i];
      p += __shfl_xor(p, 1);
      p += __shfl_xor(p, 2);
      p += __shfl_xor(p, 4);
      p += __shfl_xor(p, 8);
      lg4[e] = p * LG2SCALE;
    }
    float mx = fmaxf(fmaxf(lg4[0], lg4[1]), fmaxf(lg4[2], lg4[3]));
    if (mx > m) {
      float rr = exp2f(m - mx);  // exp2(-inf)=0 bootstraps first group
      s *= rr;
#pragma unroll
      for (int i = 0; i < 8; i++) acc[i] *= rr;
      m = mx;
    }
#pragma unroll
    for (int e = 0; e < 4; e++) {
      float w = exp2f(lg4[e] - m);
      s += w;
      float vf[8];
      dec8(make_uint2(kv4[e].z, kv4[e].w), vf);
#pragma unroll
      for (int i = 0; i < 8; i++) acc[i] += w * vf[i];
    }
  }
  // remainder singles
  for (; j < j1; ++j) {
    uint4 kv = *(const uint4*)(kvp + (size_t)csrc[j]);
    float kfA[8], vfA[8];
    dec8(make_uint2(kv.x, kv.y), kfA);
    dec8(make_uint2(kv.z, kv.w), vfA);
    float pA = 0.f;
#pragma unroll
    for (int i = 0; i < 8; i++) pA += qf[i] * kfA[i];
    pA += __shfl_xor(pA, 1);
    pA += __shfl_xor(pA, 2);
    pA += __shfl_xor(pA, 4);
    pA += __shfl_xor(pA, 8);
    float lgA = pA * LG2SCALE;
    if (lgA > m) {
      float rr = exp2f(m - lgA);
      s *= rr;
#pragma unroll
      for (int i = 0; i < 8; i++) acc[i] *= rr;
      m = lgA;
    }
    float wA = exp2f(lgA - m);
    s += wA;
#pragma unroll
    for (int i = 0; i < 8; i++) acc[i] += wA * vfA[i];
  }

  float rsel = 0.25f / (s + 1e-16f);
#pragma unroll
  for (int i = 0; i < 8; i++) {
    float a = acc[i] * rsel;
    a += __shfl_xor(a, 16);
    a += __shfl_xor(a, 32);
    acc[i] = a;
  }

  size_t hbase = (size_t)n * HIDC;
  float u[8];
  {
    float4 h0 = *(const float4*)(h + hbase + t * 8);
    float4 h1 = *(const float4*)(h + hbase + t * 8 + 4);
    float4 k0 = *(const float4*)(skipb + hbase + t * 8);
    float4 k1 = *(const float4*)(skipb + hbase + t * 8 + 4);
    u[0] = h0.x + acc[0] + k0.x; u[1] = h0.y + acc[1] + k0.y;
    u[2] = h0.z + acc[2] + k0.z; u[3] = h0.w + acc[3] + k0.w;
    u[4] = h1.x + acc[4] + k1.x; u[5] = h1.y + acc[5] + k1.y;
    u[6] = h1.z + acc[6] + k1.z; u[7] = h1.w + acc[7] + k1.w;
  }
  float su = 0.f;
#pragma unroll
  for (int i = 0; i < 8; i++) su += u[i];
#pragma unroll
  for (int d = 1; d < 16; d <<= 1) su += __shfl_xor(su, d);
  float mu = su * (1.f / 128.f);
  float vs = 0.f;
#pragma unroll
  for (int i = 0; i < 8; i++) { u[i] -= mu; vs += u[i] * u[i]; }
#pragma unroll
  for (int d = 1; d < 16; d <<= 1) vs += __shfl_xor(vs, d);
  float inv = rsqrtf(vs * (1.f / 128.f) + 1e-5f);
  if (hh == 0) {
    float4 g0 = *(const float4*)(gamma + t * 8);
    float4 g1 = *(const float4*)(gamma + t * 8 + 4);
    float4 b0 = *(const float4*)(beta + t * 8);
    float4 b1 = *(const float4*)(beta + t * 8 + 4);
    float o[8];
    o[0] = u[0] * inv * g0.x + b0.x; o[1] = u[1] * inv * g0.y + b0.y;
    o[2] = u[2] * inv * g0.z + b0.z; o[3] = u[3] * inv * g0.w + b0.w;
    o[4] = u[4] * inv * g1.x + b1.x; o[5] = u[5] * inv * g1.y + b1.y;
    o[6] = u[6] * inv * g1.z + b1.z; o[7] = u[7] * inv * g1.w + b1.w;
    *(float4*)(outp + hbase + t * 8)     = make_float4(o[0], o[1], o[2], o[3]);
    *(float4*)(outp + hbase + t * 8 + 4) = make_float4(o[4], o[5], o[6], o[7]);
    ushort4 c0 = make_ushort4(f2bf(o[0]), f2bf(o[1]), f2bf(o[2]), f2bf(o[3]));
    ushort4 c1 = make_ushort4(f2bf(o[4]), f2bf(o[5]), f2bf(o[6]), f2bf(o[7]));
    *(ushort4*)(hb_out + hbase + t * 8)     = c0;
    *(ushort4*)(hb_out + hbase + t * 8 + 4) = c1;
  }
}

// ---------------- workspace layout (float offsets, all 16B-aligned) ----------------
#define OFF_H      ((size_t)0)            // N*128 fp32
#define OFF_SKIP   ((size_t)2560000)      // N*128 fp32
#define OFF_QB     ((size_t)5120000)      // N*512 bf16
#define OFF_KV8    ((size_t)10240000)     // N*1024 fp8 (interleaved k|v per 8B)
#define OFF_HB     ((size_t)15360000)     // N*128 bf16
#define OFF_XB     ((size_t)16640000)     // N*64 bf16
#define OFF_WT     ((size_t)17280000)     // 3*1664*128 bf16
#define OFF_WINT   ((size_t)17599488)     // 128*64 bf16
#define OFF_BCAT   ((size_t)17603584)     // 3*1664 fp32
#define OFF_CSRC   ((size_t)17608576)     // E ints
#define OFF_ROW    ((size_t)17928576)     // N+1 ints
#define OFF_DEG    ((size_t)17948580)     // N ints
#define OFF_CUR    ((size_t)17968580)     // N ints

extern "C" void kernel_launch(void* const* d_in, const int* in_sizes, int n_in,
                              void* d_out, int out_size, void* d_ws, size_t ws_size,
                              hipStream_t stream) {
  const float* x    = (const float*)d_in[0];
  const int*   ei   = (const int*)d_in[1];
  const float* Win  = (const float*)d_in[2];
  const float* bin_ = (const float*)d_in[3];
  const float* Wq   = (const float*)d_in[4];
  const float* bq   = (const float*)d_in[5];
  const float* Wk   = (const float*)d_in[6];
  const float* bk   = (const float*)d_in[7];
  const float* Wv   = (const float*)d_in[8];
  const float* bv   = (const float*)d_in[9];
  const float* Wsk  = (const float*)d_in[10];
  const float* bsk  = (const float*)d_in[11];
  const float* lng  = (const float*)d_in[12];
  const float* lnb  = (const float*)d_in[13];
  float* out = (float*)d_out;
  float* ws = (float*)d_ws;

  float* h     = ws + OFF_H;
  float* skipb = ws + OFF_SKIP;
  unsigned short* qb   = (unsigned short*)(ws + OFF_QB);
  unsigned char*  kv8  = (unsigned char*)(ws + OFF_KV8);
  unsigned short* hb   = (unsigned short*)(ws + OFF_HB);
  unsigned short* xb   = (unsigned short*)(ws + OFF_XB);
  unsigned short* wT   = (unsigned short*)(ws + OFF_WT);
  unsigned short* winT = (unsigned short*)(ws + OFF_WINT);
  float* bcat  = ws + OFF_BCAT;
  int* csrc     = (int*)(ws + OFF_CSRC);
  int* rowstart = (int*)(ws + OFF_ROW);
  int* deg      = (int*)(ws + OFF_DEG);
  int* cur      = (int*)(ws + OFF_CUR);

  // ---- CSR build + weight prep (front-loaded) ----
  hipMemsetAsync(deg, 0, NN * sizeof(int), stream);
  hipMemsetAsync(cur, 0, NN * sizeof(int), stream);
  deg_hist<<<(EE + 255) / 256, 256, 0, stream>>>(ei, deg);
  scan_deg<<<1, 1024, 0, stream>>>(deg, rowstart);
  csr_scatter<<<(EE + 255) / 256, 256, 0, stream>>>(ei, rowstart, cur, csrc);

  conv_x<<<(NN * DIN / 4 + 255) / 256, 256, 0, stream>>>(x, xb);
  build_winT<<<(HIDC * DIN + 255) / 256, 256, 0, stream>>>(Win, winT);
  build_wcatT_all<<<(NL * NCOLS * HIDC + 255) / 256, 256, 0, stream>>>(
      Wq, Wk, Wv, Wsk, wT);
  build_bcat_all<<<(NL * NCOLS + 255) / 256, 256, 0, stream>>>(bq, bk, bv, bsk, bcat);

  // ---- input projection via MFMA (K=64): h fp32 + hb bf16 ----
  mfma_gemm_in<<<(NN + 127) / 128, 256, 0, stream>>>(xb, winT, bin_, hb, h);

  const int nbx = NCOLS / 64;            // 26
  const int nby = (NN + 63) / 64;        // 313
  const int nwg = nbx * nby;             // 8138

  for (int l = 0; l < NL; ++l) {
    gemm64<<<nwg, 256, 0, stream>>>(hb, wT + (size_t)l * NCOLS * HIDC,
                                    bcat + (size_t)l * NCOLS, qb, kv8, skipb,
                                    nbx, nwg);

    float* dst = (l == NL - 1) ? out : h;
    node_fused<<<(NN + 3) / 4, 256, 0, stream>>>(
        qb, kv8, skipb, h, rowstart, csrc,
        lng + (size_t)l * 128, lnb + (size_t)l * 128, dst, hb);
  }
  (void)in_sizes; (void)n_in; (void)out_size; (void)ws_size;
}